// Round 6
// baseline (942.190 us; speedup 1.0000x reference)
//
#include <hip/hip_runtime.h>
#include <hip/hip_bf16.h>
#include <hip/hip_fp16.h>
#include <math.h>

#define N_NODES 50000
#define N_EDGES 800000
#define HID 64
#define NBK 196          // buckets of 256 nodes
#define EPB 1024         // edges per hist/scatter block
#define SB  ((N_EDGES + EPB - 1) / EPB)   // 782
#define FLAT (NBK * SB)  // 153272 flattened (bucket-major) histogram entries
#define SCAN_B ((FLAT + 255) / 256)  // 599

#define QKVS0_BLKS 3125
#define SCORE_BLKS ((N_EDGES * 4) / 256)   // 12500, exact

#define BKF 32                                   // flat-agg bucket (nodes/block)
#define NBLK_FLAT ((N_NODES + BKF - 1) / BKF)    // 1563

// fused prep grid partition
#define LN0_BLKS   6250
#define HIST_BLKS  SB
#define WP0_BLKS   32    // 16*1*512 / 256
#define WP12_BLKS  64    // 16*2*512 / 256
#define PREP_BLKS  (LN0_BLKS + HIST_BLKS + WP0_BLKS + 2 * WP12_BLKS)

typedef __attribute__((ext_vector_type(8))) short short8;
typedef __attribute__((ext_vector_type(4))) float float4v;
typedef __attribute__((ext_vector_type(2))) float float2v;

__device__ __forceinline__ unsigned short f32_to_bf16_rne(float f) {
    unsigned int u = __float_as_uint(f);
    unsigned int r = u + 0x7fffu + ((u >> 16) & 1u);
    return (unsigned short)(r >> 16);
}

// fp8 e4m3fn (OCP on gfx950) helpers: HW cvt instructions.
__device__ __forceinline__ unsigned int f32_to_fp8_byte(float f) {
    return (unsigned int)__builtin_amdgcn_cvt_pk_fp8_f32(f, f, 0, false) & 0xffu;
}
template <bool HI>
__device__ __forceinline__ float2v fp8x2_to_f32(unsigned int w) {
    return __builtin_amdgcn_cvt_pk_f32_fp8((int)w, HI);
}
__device__ __forceinline__ float2 h2_to_f32(unsigned int w) {
    __half2 h = *reinterpret_cast<__half2*>(&w);
    return __half22float2(h);
}

// ---------------------------------------------------------------------------
// Device helpers for the fused prep kernel.
__device__ __forceinline__ void ln0_body(int b, int t,
        const float* __restrict__ x, const float* __restrict__ g,
        const float* __restrict__ bb, float* __restrict__ h0) {
    int lane = t & 63;
    int n = b * 8 + (t >> 6) * 2 + (lane >> 5);
    int c = lane & 31;
    float v = x[n * 32 + c];
    float s = v;
    #pragma unroll
    for (int off = 1; off < 32; off <<= 1) s += __shfl_xor(s, off);
    float mu = s * (1.0f / 32.0f);
    float d = v - mu;
    float vs = d * d;
    #pragma unroll
    for (int off = 1; off < 32; off <<= 1) vs += __shfl_xor(vs, off);
    float var = vs * (1.0f / 32.0f);
    h0[n * 32 + c] = d * rsqrtf(var + 1e-5f) * g[c] + bb[c];
}

__device__ __forceinline__ void wprep_body(int idx, int KS,
        const float* __restrict__ Wq, const float* __restrict__ Wk,
        const float* __restrict__ Wv, const float* __restrict__ Ws,
        unsigned short* __restrict__ Wp) {
    int j = idx & 7;
    int lane = (idx >> 3) & 63;
    int ts = idx >> 9;            // tile*KS + s
    int s = ts % KS;
    int tile = ts / KS;
    int which = tile >> 2;
    int slice = tile & 3;
    int k = s * 32 + ((lane >> 4) * 8) + j;
    int col = slice * 16 + (lane & 15);
    const float* W = (which == 0) ? Wq : (which == 1) ? Wk : (which == 2) ? Wv : Ws;
    Wp[idx] = f32_to_bf16_rne(W[k * 64 + col]);
}

// ---------------------------------------------------------------------------
// Fused prep: ln0 + per-block bucket histogram + 3x weight pack.
__global__ __launch_bounds__(256) void prep_kernel(
        const float* __restrict__ x, const float* __restrict__ ln0g,
        const float* __restrict__ ln0b, float* __restrict__ h0,
        const int* __restrict__ dst, int* __restrict__ ghist,
        const float* __restrict__ Wq0, const float* __restrict__ Wk0,
        const float* __restrict__ Wv0, const float* __restrict__ Ws0,
        unsigned short* __restrict__ Wp0,
        const float* __restrict__ Wq1, const float* __restrict__ Wk1,
        const float* __restrict__ Wv1, const float* __restrict__ Ws1,
        unsigned short* __restrict__ Wp1,
        const float* __restrict__ Wq2, const float* __restrict__ Wk2,
        const float* __restrict__ Wv2, const float* __restrict__ Ws2,
        unsigned short* __restrict__ Wp2) {
    __shared__ int hist[NBK];
    int b = blockIdx.x;
    int t = threadIdx.x;
    if (b < LN0_BLKS) {
        ln0_body(b, t, x, ln0g, ln0b, h0);
    } else if (b < LN0_BLKS + HIST_BLKS) {
        int i = b - LN0_BLKS;
        for (int k = t; k < NBK; k += 256) hist[k] = 0;
        __syncthreads();
        int e0 = i * EPB;
        #pragma unroll
        for (int r = 0; r < EPB / 256; r++) {
            int e = e0 + r * 256 + t;
            if (e < N_EDGES) atomicAdd(&hist[dst[e] >> 8], 1);
        }
        __syncthreads();
        for (int k = t; k < NBK; k += 256) ghist[k * SB + i] = hist[k];
    } else if (b < LN0_BLKS + HIST_BLKS + WP0_BLKS) {
        int idx = (b - LN0_BLKS - HIST_BLKS) * 256 + t;
        wprep_body(idx, 1, Wq0, Wk0, Wv0, Ws0, Wp0);
    } else if (b < LN0_BLKS + HIST_BLKS + WP0_BLKS + WP12_BLKS) {
        int idx = (b - LN0_BLKS - HIST_BLKS - WP0_BLKS) * 256 + t;
        wprep_body(idx, 2, Wq1, Wk1, Wv1, Ws1, Wp1);
    } else {
        int idx = (b - LN0_BLKS - HIST_BLKS - WP0_BLKS - WP12_BLKS) * 256 + t;
        wprep_body(idx, 2, Wq2, Wk2, Wv2, Ws2, Wp2);
    }
}

// ---------------------------------------------------------------------------
// CSR build scans (deterministic, no global atomics).
__global__ void scan1_kernel(const int* __restrict__ ghist, int* __restrict__ csum) {
    int f = blockIdx.x * 256 + threadIdx.x;
    int v = (f < FLAT) ? ghist[f] : 0;
    #pragma unroll
    for (int off = 1; off < 64; off <<= 1) v += __shfl_xor(v, off);
    __shared__ int ws[4];
    if ((threadIdx.x & 63) == 0) ws[threadIdx.x >> 6] = v;
    __syncthreads();
    if (threadIdx.x == 0) csum[blockIdx.x] = ws[0] + ws[1] + ws[2] + ws[3];
}

__global__ void scan2_kernel(const int* __restrict__ csum, int* __restrict__ coff,
                             int* __restrict__ bbase, int* __restrict__ row_ptr) {
    int lane = threadIdx.x;
    int carry = 0;
    for (int base = 0; base < SCAN_B; base += 64) {
        int i = base + lane;
        int v = (i < SCAN_B) ? csum[i] : 0;
        int incl = v;
        #pragma unroll
        for (int off = 1; off < 64; off <<= 1) {
            int tt = __shfl_up(incl, off);
            if (lane >= off) incl += tt;
        }
        if (i < SCAN_B) coff[i] = carry + incl - v;
        carry += __shfl(incl, 63);
    }
    if (lane == 0) { bbase[NBK] = N_EDGES; row_ptr[N_NODES] = N_EDGES; }
}

__global__ void scan3_kernel(const int* __restrict__ ghist, const int* __restrict__ coff,
                             int* __restrict__ goff, int* __restrict__ bbase) {
    int f = blockIdx.x * 256 + threadIdx.x;
    int lane = threadIdx.x & 63;
    int w = threadIdx.x >> 6;
    int v = (f < FLAT) ? ghist[f] : 0;
    int incl = v;
    #pragma unroll
    for (int off = 1; off < 64; off <<= 1) {
        int tt = __shfl_up(incl, off);
        if (lane >= off) incl += tt;
    }
    __shared__ int ws[4];
    if (lane == 63) ws[w] = incl;
    __syncthreads();
    int woff = 0;
    #pragma unroll
    for (int k = 0; k < 4; k++) if (k < w) woff += ws[k];
    int excl = coff[blockIdx.x] + woff + incl - v;
    if (f < FLAT) {
        goff[f] = excl;
        if (f % SB == 0) bbase[f / SB] = excl;
    }
}

// ---------------------------------------------------------------------------
// Q/K/V/Skip projection body via MFMA. Block = 16 nodes; wave w owns the
// 16-col slice w of each of Q,K,V,S. fp32 accum; biases in fp32.
// Outputs: QS = (bf16(S)<<16)|bf16(Q*scale)  (stream; R1-proven precision)
//          K8 = fp8 e4m3 row of 64B; Vh = fp16 row of 128B.
template <int D>
__device__ __forceinline__ void qkvs_body(int bid, int t,
        const float* __restrict__ h,
        const unsigned short* __restrict__ Wp,
        const float* __restrict__ bq, const float* __restrict__ bk,
        const float* __restrict__ bv, float scale,
        unsigned int* __restrict__ QS,
        unsigned int* __restrict__ K8, uint2* __restrict__ Vh) {
    constexpr int KS = D / 32;
    int lane = t & 63;
    int w = t >> 6;
    int n0 = bid * 16;
    int n16 = lane & 15;
    int quad = lane >> 4;
    int col = w * 16 + n16;

    short8 afrag[KS];
    #pragma unroll
    for (int s = 0; s < KS; s++) {
        const float* hp = &h[(n0 + n16) * D + s * 32 + quad * 8];
        float4 a0 = *(const float4*)hp;
        float4 a1 = *(const float4*)(hp + 4);
        short8 af;
        af[0] = (short)f32_to_bf16_rne(a0.x);
        af[1] = (short)f32_to_bf16_rne(a0.y);
        af[2] = (short)f32_to_bf16_rne(a0.z);
        af[3] = (short)f32_to_bf16_rne(a0.w);
        af[4] = (short)f32_to_bf16_rne(a1.x);
        af[5] = (short)f32_to_bf16_rne(a1.y);
        af[6] = (short)f32_to_bf16_rne(a1.z);
        af[7] = (short)f32_to_bf16_rne(a1.w);
        afrag[s] = af;
    }

    float4v accs[4];
    #pragma unroll
    for (int which = 0; which < 4; which++) {
        float4v acc = {0.0f, 0.0f, 0.0f, 0.0f};
        int tile = which * 4 + w;
        #pragma unroll
        for (int s = 0; s < KS; s++) {
            short8 bfrag = *(const short8*)&Wp[((tile * KS + s) * 64 + lane) * 8];
            acc = __builtin_amdgcn_mfma_f32_16x16x32_bf16(afrag[s], bfrag, acc, 0, 0, 0);
        }
        accs[which] = acc;
    }

    float bqc = bq[col], bkc = bk[col], bvc = bv[col];
    int j = n16 & 3;                    // byte/half position within 4-channel word
    int mword = (col >> 2);             // 4-channel word index 0..15

    #pragma unroll
    for (int r = 0; r < 4; r++) {
        int node = n0 + quad * 4 + r;
        unsigned int qw = f32_to_bf16_rne((accs[0][r] + bqc) * scale);
        unsigned int sw = f32_to_bf16_rne(accs[3][r]);
        QS[node * 64 + col] = (sw << 16) | qw;
        // fp8-pack K: 4 consecutive channels -> one dword, via shfl-OR
        unsigned int ku = f32_to_fp8_byte(accs[1][r] + bkc) << (8 * j);
        ku |= __shfl_xor(ku, 1); ku |= __shfl_xor(ku, 2);
        // fp16-pack V: 4 consecutive channels -> uint2 {c0|c1<<16, c2|c3<<16}
        unsigned int hb = (unsigned int)__half_as_ushort(__float2half_rn(accs[2][r] + bvc));
        unsigned int vx = (j < 2) ? (hb << (16 * j)) : 0u;
        unsigned int vy = (j >= 2) ? (hb << (16 * (j - 2))) : 0u;
        vx |= __shfl_xor(vx, 1); vx |= __shfl_xor(vx, 2);
        vy |= __shfl_xor(vy, 1); vy |= __shfl_xor(vy, 2);
        if (j == 0) {
            K8[node * 16 + mword] = ku;
            Vh[node * 16 + mword] = make_uint2(vx, vy);
        }
    }
}

template <int D>
__global__ __launch_bounds__(256) void qkvs_mfma_kernel(
        const float* __restrict__ h,
        const unsigned short* __restrict__ Wp,
        const float* __restrict__ bq, const float* __restrict__ bk,
        const float* __restrict__ bv, float scale,
        unsigned int* __restrict__ QS,
        unsigned int* __restrict__ K8, uint2* __restrict__ Vh) {
    qkvs_body<D>(blockIdx.x, threadIdx.x, h, Wp, bq, bk, bv, scale, QS, K8, Vh);
}

// ---------------------------------------------------------------------------
// Fused scatter + layer-0 QKVS (independent work; fills the CUs).
__global__ __launch_bounds__(256) void scatter_qkvs0_kernel(
        const int* __restrict__ src, const int* __restrict__ dst,
        const int* __restrict__ goff, int2* __restrict__ ebkt,
        const float* __restrict__ h, const unsigned short* __restrict__ Wp,
        const float* __restrict__ bq, const float* __restrict__ bk,
        const float* __restrict__ bv, float scale,
        unsigned int* __restrict__ QS,
        unsigned int* __restrict__ K8, uint2* __restrict__ Vh) {
    __shared__ int hist[NBK];
    int t = threadIdx.x;
    if (blockIdx.x < SB) {
        int i = blockIdx.x;
        for (int k = t; k < NBK; k += 256) hist[k] = 0;
        __syncthreads();
        int e0 = i * EPB;
        #pragma unroll
        for (int r = 0; r < EPB / 256; r++) {
            int e = e0 + r * 256 + t;
            if (e < N_EDGES) {
                int s = src[e], d = dst[e];
                int k = d >> 8;
                int rank = atomicAdd(&hist[k], 1);
                ebkt[goff[k * SB + i] + rank] = make_int2(s, d);
            }
        }
    } else {
        qkvs_body<32>(blockIdx.x - SB, t, h, Wp, bq, bk, bv, scale, QS, K8, Vh);
    }
}

// bucket_build emits colb2 = (src, dst) pairs in CSR order.
__global__ __launch_bounds__(256) void bucket_build_kernel(
        const int2* __restrict__ ebkt, const int* __restrict__ bbase,
        int* __restrict__ row_ptr, int2* __restrict__ colb2) {
    __shared__ int ldeg[256];
    __shared__ int lcur[256];
    __shared__ int wsum[4];
    int b = blockIdx.x;
    int t = threadIdx.x;
    int cbase = bbase[b];
    int cnt = bbase[b + 1] - cbase;

    ldeg[t] = 0;
    __syncthreads();
    for (int i = t; i < cnt; i += 256) {
        int2 e = ebkt[cbase + i];
        atomicAdd(&ldeg[e.y & 255], 1);
    }
    __syncthreads();

    int lane = t & 63;
    int w = t >> 6;
    int v = ldeg[t];
    int incl = v;
    #pragma unroll
    for (int off = 1; off < 64; off <<= 1) {
        int tt = __shfl_up(incl, off);
        if (lane >= off) incl += tt;
    }
    if (lane == 63) wsum[w] = incl;
    __syncthreads();
    int woff = 0;
    #pragma unroll
    for (int k = 0; k < 4; k++) if (k < w) woff += wsum[k];
    int excl = woff + incl - v;

    int node = b * 256 + t;
    if (node < N_NODES) row_ptr[node] = cbase + excl;
    lcur[t] = excl;
    __syncthreads();

    for (int i = t; i < cnt; i += 256) {
        int2 e = ebkt[cbase + i];
        int r = atomicAdd(&lcur[e.y & 255], 1);
        colb2[cbase + r] = e;
    }
}

// ---------------------------------------------------------------------------
// Edge-parallel score+exp (proven 17us structure): lane = (edge, head).
template <int HEADS>
__global__ __launch_bounds__(256) void score_kernel(
        const unsigned int* __restrict__ QS,
        const unsigned int* __restrict__ K8,
        const int2* __restrict__ colb2,
        float* __restrict__ p) {
    int gid = blockIdx.x * 256 + threadIdx.x;
    int e = gid >> 2;
    int slot = gid & 3;
    int2 ed = colb2[e];
    const unsigned int* qp = &QS[(size_t)ed.y * 64 + slot * 16];
    uint4 qa = *(const uint4*)qp;
    uint4 qb = *(const uint4*)(qp + 4);
    uint4 qc = *(const uint4*)(qp + 8);
    uint4 qd = *(const uint4*)(qp + 12);
    uint4 kw = *(const uint4*)&K8[(size_t)ed.x * 16 + slot * 4];

    float2v k0 = fp8x2_to_f32<false>(kw.x), k1 = fp8x2_to_f32<true>(kw.x);
    float2v k2 = fp8x2_to_f32<false>(kw.y), k3 = fp8x2_to_f32<true>(kw.y);
    float2v k4 = fp8x2_to_f32<false>(kw.z), k5 = fp8x2_to_f32<true>(kw.z);
    float2v k6 = fp8x2_to_f32<false>(kw.w), k7 = fp8x2_to_f32<true>(kw.w);

    float t;
    t =      __uint_as_float(qa.x << 16) * k0.x;
    t = fmaf(__uint_as_float(qa.y << 16), k0.y, t);
    t = fmaf(__uint_as_float(qa.z << 16), k1.x, t);
    t = fmaf(__uint_as_float(qa.w << 16), k1.y, t);
    t = fmaf(__uint_as_float(qb.x << 16), k2.x, t);
    t = fmaf(__uint_as_float(qb.y << 16), k2.y, t);
    t = fmaf(__uint_as_float(qb.z << 16), k3.x, t);
    t = fmaf(__uint_as_float(qb.w << 16), k3.y, t);
    t = fmaf(__uint_as_float(qc.x << 16), k4.x, t);
    t = fmaf(__uint_as_float(qc.y << 16), k4.y, t);
    t = fmaf(__uint_as_float(qc.z << 16), k5.x, t);
    t = fmaf(__uint_as_float(qc.w << 16), k5.y, t);
    t = fmaf(__uint_as_float(qd.x << 16), k6.x, t);
    t = fmaf(__uint_as_float(qd.y << 16), k6.y, t);
    t = fmaf(__uint_as_float(qd.z << 16), k7.x, t);
    t = fmaf(__uint_as_float(qd.w << 16), k7.y, t);

    if (HEADS == 1) {
        t += __shfl_xor(t, 1);
        t += __shfl_xor(t, 2);
    }
    float pv = __expf(t);
    if (HEADS == 4) {
        p[(size_t)e * 4 + slot] = pv;
    } else {
        if (slot == 0) p[e] = pv;
    }
}

// ---------------------------------------------------------------------------
// FLAT bucket aggregation (layers 0/1, heads=4): one block per 32-node bucket,
// edge-parallel uniform loop (2-stage pipeline), p*V accumulated into LDS via
// ds_add_f32 (dst is bucket-local by CSR construction), then per-node LN
// epilogue in-block. No per-node serial gather loop — this is the structural
// escape from the ~60us latency-serialization floor (R5 post-mortem).
template <bool RES>
__global__ __launch_bounds__(256) void flat_agg_kernel(
        const unsigned int* __restrict__ QS,
        const uint2* __restrict__ Vh,
        const float* __restrict__ p,
        const int2* __restrict__ colb2,
        const int* __restrict__ row_ptr,
        const float* __restrict__ g, const float* __restrict__ b,
        const float* __restrict__ h_in, float* __restrict__ h_out) {
    __shared__ float shAcc[BKF][HID];
    __shared__ float shSum[BKF][4];
    int t = threadIdx.x;
    int n0 = blockIdx.x * BKF;

    for (int i = t; i < BKF * HID; i += 256) ((float*)shAcc)[i] = 0.0f;
    for (int i = t; i < BKF * 4; i += 256) ((float*)shSum)[i] = 0.0f;
    __syncthreads();

    int lane = t & 63;
    int wid = t >> 6;
    int m = lane & 15;
    int eg = lane >> 4;
    int hsel = m >> 2;

    int ebeg = row_ptr[n0];
    int eend = row_ptr[min(n0 + BKF, N_NODES)];

    // 2-stage pipeline: prefetch next (colb2, p) while V-gather is in flight.
    int eb = ebeg + wid * 4;
    int eA = eb + eg;
    bool okA = eA < eend;
    int2 sdA = okA ? colb2[eA] : make_int2(0, n0);
    float pA = okA ? p[(size_t)eA * 4 + hsel] : 0.0f;

    for (; eb < eend; eb += 16) {
        uint2 vh = Vh[(size_t)sdA.x * 16 + m];   // gather for current
        int eB = eb + 16 + eg;
        bool okB = eB < eend;
        int2 sdB = okB ? colb2[eB] : make_int2(0, n0);
        float pB = okB ? p[(size_t)eB * 4 + hsel] : 0.0f;

        int ln = sdA.y - n0;
        float2 v0 = h2_to_f32(vh.x), v1 = h2_to_f32(vh.y);
        atomicAdd(&shAcc[ln][4 * m + 0], pA * v0.x);
        atomicAdd(&shAcc[ln][4 * m + 1], pA * v0.y);
        atomicAdd(&shAcc[ln][4 * m + 2], pA * v1.x);
        atomicAdd(&shAcc[ln][4 * m + 3], pA * v1.y);
        if ((m & 3) == 0) atomicAdd(&shSum[ln][hsel], pA);

        sdA = sdB; pA = pB;
    }
    __syncthreads();

    // epilogue: 2 passes x (4 waves x 4 groups) = 32 nodes; group = one node.
    int grp = lane >> 4;
    #pragma unroll
    for (int pp = 0; pp < 2; pp++) {
        int ln = pp * 16 + wid * 4 + grp;
        int n = n0 + ln;
        if (n < N_NODES) {
            float4 av = *(float4*)&shAcc[ln][4 * m];
            float ssum = shSum[ln][hsel];
            float inv = 1.0f / (ssum + 1e-16f);
            uint4 qsw = *(const uint4*)&QS[(size_t)n * 64 + 4 * m];
            float o0 = fmaf(av.x, inv, __uint_as_float(qsw.x & 0xffff0000u));
            float o1 = fmaf(av.y, inv, __uint_as_float(qsw.y & 0xffff0000u));
            float o2 = fmaf(av.z, inv, __uint_as_float(qsw.z & 0xffff0000u));
            float o3 = fmaf(av.w, inv, __uint_as_float(qsw.w & 0xffff0000u));

            float s = (o0 + o1) + (o2 + o3);
            #pragma unroll
            for (int off = 1; off < 16; off <<= 1) s += __shfl_xor(s, off);
            float mu = s * (1.0f / 64.0f);
            float d0 = o0 - mu, d1 = o1 - mu, d2 = o2 - mu, d3 = o3 - mu;
            float vs = (d0 * d0 + d1 * d1) + (d2 * d2 + d3 * d3);
            #pragma unroll
            for (int off = 1; off < 16; off <<= 1) vs += __shfl_xor(vs, off);
            float rstd = rsqrtf(vs * (1.0f / 64.0f) + 1e-5f);

            float4 gv = *(const float4*)&g[4 * m];
            float4 bv = *(const float4*)&b[4 * m];
            float y0 = d0 * rstd * gv.x + bv.x;
            float y1 = d1 * rstd * gv.y + bv.y;
            float y2 = d2 * rstd * gv.z + bv.z;
            float y3 = d3 * rstd * gv.w + bv.w;
            if (RES) {
                float4 rv = *(const float4*)&h_in[(size_t)n * 64 + 4 * m];
                y0 = fmaf(0.1f, rv.x, y0);
                y1 = fmaf(0.1f, rv.y, y1);
                y2 = fmaf(0.1f, rv.z, y2);
                y3 = fmaf(0.1f, rv.w, y3);
            }
            y0 = fmaxf(y0, 0.0f); y1 = fmaxf(y1, 0.0f);
            y2 = fmaxf(y2, 0.0f); y3 = fmaxf(y3, 0.0f);
            float4 yv = make_float4(y0, y1, y2, y3);
            *(float4*)&h_out[(size_t)n * 64 + 4 * m] = yv;
        }
    }
}

// ---------------------------------------------------------------------------
// Layer-2 per-node agg (R3-proven structure): one wave per node, 16-edge
// batched gathers via bpermute; heads=1; fused MLP heads epilogue.
template <int HEADS, bool RES, bool RELU, bool HEAD>
__global__ __launch_bounds__(256) void agg_kernel(
                           const unsigned int* __restrict__ QS,
                           const unsigned int* __restrict__ K8,
                           const uint2* __restrict__ Vh,
                           const int* __restrict__ row_ptr, const int2* __restrict__ colb2,
                           const float* __restrict__ g, const float* __restrict__ b,
                           const float* __restrict__ h_in, float* __restrict__ h_out,
                           const float* __restrict__ Wr1, const float* __restrict__ br1,
                           const float* __restrict__ Wr2, const float* __restrict__ br2,
                           const float* __restrict__ Wt1, const float* __restrict__ bt1,
                           const float* __restrict__ Wt2, const float* __restrict__ bt2,
                           float* __restrict__ out) {
    constexpr int C = HID / HEADS;
    int lane = threadIdx.x & 63;
    int m = lane & 15;
    int grp = lane >> 4;
    int n = blockIdx.x * 4 + (threadIdx.x >> 6);

    uint4 qsw = *(const uint4*)&QS[(size_t)n * 64 + 4 * m];
    float4 q4 = make_float4(__uint_as_float(qsw.x << 16),
                            __uint_as_float(qsw.y << 16),
                            __uint_as_float(qsw.z << 16),
                            __uint_as_float(qsw.w << 16));

    int beg = row_ptr[n], end = row_ptr[n + 1];

    float ssum = 0.0f;
    float acc0 = 0.0f, acc1 = 0.0f, acc2 = 0.0f, acc3 = 0.0f;

    for (int base = beg; base < end; base += 64) {
        int limit = min(end - base, 64);
        int src_l = (base + lane < end) ? colb2[base + lane].x : 0;
        for (int sub = 0; sub < limit; sub += 16) {
            int e0 = sub + grp, e1 = sub + 4 + grp, e2 = sub + 8 + grp, e3 = sub + 12 + grp;
            int s0 = __shfl(src_l, e0);
            int s1 = __shfl(src_l, e1);
            int s2 = __shfl(src_l, e2);
            int s3 = __shfl(src_l, e3);
            bool v0ok = e0 < limit, v1ok = e1 < limit, v2ok = e2 < limit, v3ok = e3 < limit;
            unsigned int ka0 = 0, ka1 = 0, ka2 = 0, ka3 = 0;
            uint2 va0 = make_uint2(0, 0), va1 = va0, va2 = va0, va3 = va0;
            if (v0ok) { ka0 = K8[(size_t)s0 * 16 + m]; va0 = Vh[(size_t)s0 * 16 + m]; }
            if (v1ok) { ka1 = K8[(size_t)s1 * 16 + m]; va1 = Vh[(size_t)s1 * 16 + m]; }
            if (v2ok) { ka2 = K8[(size_t)s2 * 16 + m]; va2 = Vh[(size_t)s2 * 16 + m]; }
            if (v3ok) { ka3 = K8[(size_t)s3 * 16 + m]; va3 = Vh[(size_t)s3 * 16 + m]; }

            float2v k0a = fp8x2_to_f32<false>(ka0), k0b = fp8x2_to_f32<true>(ka0);
            float2v k1a = fp8x2_to_f32<false>(ka1), k1b = fp8x2_to_f32<true>(ka1);
            float2v k2a = fp8x2_to_f32<false>(ka2), k2b = fp8x2_to_f32<true>(ka2);
            float2v k3a = fp8x2_to_f32<false>(ka3), k3b = fp8x2_to_f32<true>(ka3);

            float t0 = fmaf(q4.x, k0a.x, fmaf(q4.y, k0a.y,
                       fmaf(q4.z, k0b.x, q4.w * k0b.y)));
            float t1 = fmaf(q4.x, k1a.x, fmaf(q4.y, k1a.y,
                       fmaf(q4.z, k1b.x, q4.w * k1b.y)));
            float t2 = fmaf(q4.x, k2a.x, fmaf(q4.y, k2a.y,
                       fmaf(q4.z, k2b.x, q4.w * k2b.y)));
            float t3 = fmaf(q4.x, k3a.x, fmaf(q4.y, k3a.y,
                       fmaf(q4.z, k3b.x, q4.w * k3b.y)));
            #pragma unroll
            for (int off = 1; off < C / 4; off <<= 1) {
                t0 += __shfl_xor(t0, off);
                t1 += __shfl_xor(t1, off);
                t2 += __shfl_xor(t2, off);
                t3 += __shfl_xor(t3, off);
            }
            float p0 = v0ok ? __expf(t0) : 0.0f;
            float p1 = v1ok ? __expf(t1) : 0.0f;
            float p2 = v2ok ? __expf(t2) : 0.0f;
            float p3 = v3ok ? __expf(t3) : 0.0f;
            ssum += (p0 + p1) + (p2 + p3);

            float2 v0a = h2_to_f32(va0.x), v0b = h2_to_f32(va0.y);
            float2 v1a = h2_to_f32(va1.x), v1b = h2_to_f32(va1.y);
            float2 v2a = h2_to_f32(va2.x), v2b = h2_to_f32(va2.y);
            float2 v3a = h2_to_f32(va3.x), v3b = h2_to_f32(va3.y);

            acc0 = fmaf(p0, v0a.x, fmaf(p1, v1a.x,
                   fmaf(p2, v2a.x, fmaf(p3, v3a.x, acc0))));
            acc1 = fmaf(p0, v0a.y, fmaf(p1, v1a.y,
                   fmaf(p2, v2a.y, fmaf(p3, v3a.y, acc1))));
            acc2 = fmaf(p0, v0b.x, fmaf(p1, v1b.x,
                   fmaf(p2, v2b.x, fmaf(p3, v3b.x, acc2))));
            acc3 = fmaf(p0, v0b.y, fmaf(p1, v1b.y,
                   fmaf(p2, v2b.y, fmaf(p3, v3b.y, acc3))));
        }
    }

    #pragma unroll
    for (int off = 16; off < 64; off <<= 1) {
        ssum += __shfl_xor(ssum, off);
        acc0 += __shfl_xor(acc0, off);
        acc1 += __shfl_xor(acc1, off);
        acc2 += __shfl_xor(acc2, off);
        acc3 += __shfl_xor(acc3, off);
    }

    float inv = 1.0f / (ssum + 1e-16f);
    float o0 = fmaf(acc0, inv, __uint_as_float(qsw.x & 0xffff0000u));
    float o1 = fmaf(acc1, inv, __uint_as_float(qsw.y & 0xffff0000u));
    float o2 = fmaf(acc2, inv, __uint_as_float(qsw.z & 0xffff0000u));
    float o3 = fmaf(acc3, inv, __uint_as_float(qsw.w & 0xffff0000u));

    float s = (o0 + o1) + (o2 + o3);
    #pragma unroll
    for (int off = 1; off < 16; off <<= 1) s += __shfl_xor(s, off);
    float mu = s * (1.0f / 64.0f);
    float d0 = o0 - mu, d1 = o1 - mu, d2 = o2 - mu, d3 = o3 - mu;
    float vs = (d0 * d0 + d1 * d1) + (d2 * d2 + d3 * d3);
    #pragma unroll
    for (int off = 1; off < 16; off <<= 1) vs += __shfl_xor(vs, off);
    float rstd = rsqrtf(vs * (1.0f / 64.0f) + 1e-5f);

    float4 gv = *(const float4*)&g[4 * m];
    float4 bv = *(const float4*)&b[4 * m];
    float y0 = d0 * rstd * gv.x + bv.x;
    float y1 = d1 * rstd * gv.y + bv.y;
    float y2 = d2 * rstd * gv.z + bv.z;
    float y3 = d3 * rstd * gv.w + bv.w;
    if (RES) {
        float4 rv = *(const float4*)&h_in[(size_t)n * 64 + 4 * m];
        y0 = fmaf(0.1f, rv.x, y0);
        y1 = fmaf(0.1f, rv.y, y1);
        y2 = fmaf(0.1f, rv.z, y2);
        y3 = fmaf(0.1f, rv.w, y3);
    }
    if (RELU) {
        y0 = fmaxf(y0, 0.0f); y1 = fmaxf(y1, 0.0f);
        y2 = fmaxf(y2, 0.0f); y3 = fmaxf(y3, 0.0f);
    }

    if (!HEAD) {
        if (grp == 0) {
            float4 yv = make_float4(y0, y1, y2, y3);
            *(float4*)&h_out[(size_t)n * 64 + 4 * m] = yv;
        }
    } else {
        __shared__ float sh[4][HID];
        int wave = threadIdx.x >> 6;
        if (grp == 0) {
            float4 yv = make_float4(y0, y1, y2, y3);
            *(float4*)&sh[wave][4 * m] = yv;
        }
        __syncthreads();
        int half = lane >> 5;
        int j = lane & 31;
        const float* W1 = half ? Wt1 : Wr1;
        const float* b1 = half ? bt1 : br1;
        const float* W2 = half ? Wt2 : Wr2;
        const float* b2v = half ? bt2 : br2;
        float a = b1[j];
        #pragma unroll 8
        for (int i = 0; i < 64; i++) a = fmaf(sh[wave][i], W1[i * 32 + j], a);
        a = fmaxf(a, 0.0f);
        float r = a * W2[j];
        #pragma unroll
        for (int off = 1; off < 32; off <<= 1) r += __shfl_xor(r, off);
        if (j == 0) out[n * 2 + half] = r + b2v[0];
    }
}

// ---------------------------------------------------------------------------
extern "C" void kernel_launch(void* const* d_in, const int* in_sizes, int n_in,
                              void* d_out, int out_size, void* d_ws, size_t ws_size,
                              hipStream_t stream) {
    const float* x    = (const float*)d_in[0];
    const int*   ei   = (const int*)d_in[1];
    const int*   src  = ei;
    const int*   dst  = ei + N_EDGES;
    const float* ln0g = (const float*)d_in[2];
    const float* ln0b = (const float*)d_in[3];

    const float* P[27];
    for (int i = 0; i < 27; i++) P[i] = (const float*)d_in[4 + i];
    const float* Wr1 = (const float*)d_in[31];
    const float* br1 = (const float*)d_in[32];
    const float* Wr2 = (const float*)d_in[33];
    const float* br2 = (const float*)d_in[34];
    const float* Wt1 = (const float*)d_in[35];
    const float* bt1 = (const float*)d_in[36];
    const float* Wt2 = (const float*)d_in[37];
    const float* bt2 = (const float*)d_in[38];

    float* out = (float*)d_out;

    // workspace layout
    float* hbuf0 = (float*)d_ws;                 // N*64
    float* hbuf1 = hbuf0 + N_NODES * 64;         // N*64
    unsigned int* QSb = (unsigned int*)(hbuf1 + N_NODES * 64); // N*64 uint
    unsigned int* K8 = QSb + N_NODES * 64;       // N*16 uint (64B fp8 rows)
    uint2* Vh    = (uint2*)(K8 + N_NODES * 16);  // N*16 uint2 (128B fp16 rows)
    float* pbuf  = (float*)(Vh + N_NODES * 16);  // E*4 f32 (edge-head probs)
    int* row_ptr = (int*)(pbuf + (size_t)N_EDGES * 4); // N+2 (pad for colb2 align)
    int2* colb2  = (int2*)(row_ptr + (N_NODES + 2));   // E int2 (src,dst)
    int* ghist   = (int*)(colb2 + N_EDGES);      // FLAT
    int* goff    = ghist + FLAT;                 // FLAT
    int* csum    = goff + FLAT;                  // SCAN_B
    int* coff    = csum + SCAN_B;                // SCAN_B
    int* bbase   = coff + SCAN_B;                // NBK+1
    unsigned short* Wp0 = (unsigned short*)(bbase + NBK + 1); // 16*1*512
    unsigned short* Wp1 = Wp0 + 16 * 1 * 512;                 // 16*2*512
    unsigned short* Wp2 = Wp1 + 16 * 2 * 512;                 // 16*2*512
    // ebkt aliases hbuf1 (dead until agg0 writes it): E int2 = 6.4 MB < 12.8 MB
    int2* ebkt = (int2*)hbuf1;

    // ---- fused prep (ln0 + bucket hist + weight packs) ----
    prep_kernel<<<PREP_BLKS, 256, 0, stream>>>(x, ln0g, ln0b, hbuf0,
        dst, ghist,
        P[0],  P[2],  P[4],  P[6],  Wp0,
        P[9],  P[11], P[13], P[15], Wp1,
        P[18], P[20], P[22], P[24], Wp2);
    // ---- CSR build (deterministic counting sort, separate kernels) ----
    scan1_kernel<<<SCAN_B, 256, 0, stream>>>(ghist, csum);
    scan2_kernel<<<1, 64, 0, stream>>>(csum, coff, bbase, row_ptr);
    scan3_kernel<<<SCAN_B, 256, 0, stream>>>(ghist, coff, goff, bbase);
    // ---- scatter + layer-0 QKVS fused (independent work, fills the CUs) ----
    scatter_qkvs0_kernel<<<SB + QKVS0_BLKS, 256, 0, stream>>>(src, dst, goff, ebkt,
        hbuf0, Wp0, P[1], P[3], P[5], 0.25f, QSb, K8, Vh);
    bucket_build_kernel<<<NBK, 256, 0, stream>>>(ebkt, bbase, row_ptr, colb2);

    // ---- layer 0: 32 -> 64, heads=4, no residual, relu ----
    score_kernel<4><<<SCORE_BLKS, 256, 0, stream>>>(QSb, K8, colb2, pbuf);
    flat_agg_kernel<false><<<NBLK_FLAT, 256, 0, stream>>>(QSb, Vh, pbuf,
        colb2, row_ptr, P[7], P[8], nullptr, hbuf1);

    // ---- layer 1: 64 -> 64, heads=4, residual, relu ----
    qkvs_mfma_kernel<64><<<3125, 256, 0, stream>>>(hbuf1, Wp1,
        P[10], P[12], P[14], 0.25f, QSb, K8, Vh);
    score_kernel<4><<<SCORE_BLKS, 256, 0, stream>>>(QSb, K8, colb2, pbuf);
    flat_agg_kernel<true><<<NBLK_FLAT, 256, 0, stream>>>(QSb, Vh, pbuf,
        colb2, row_ptr, P[16], P[17], hbuf1, hbuf0);

    // ---- layer 2: 64 -> 64, heads=1, residual, no relu + fused MLP heads ----
    qkvs_mfma_kernel<64><<<3125, 256, 0, stream>>>(hbuf0, Wp2,
        P[19], P[21], P[23], 0.125f, QSb, K8, Vh);
    agg_kernel<1, true, false, true><<<12500, 256, 0, stream>>>(QSb, K8, Vh,
        row_ptr, colb2, P[25], P[26], hbuf0, hbuf1,
        Wr1, br1, Wr2, br2, Wt1, bt1, Wt2, bt2, out);
}

// Round 7
// 386.836 us; speedup vs baseline: 2.4356x; 2.4356x over previous
//
#include <hip/hip_runtime.h>
#include <hip/hip_bf16.h>
#include <math.h>

#define N_NODES 50000
#define N_EDGES 800000
#define HID 64
#define EPB 1024         // edges per deg/scatter block
#define SB  ((N_EDGES + EPB - 1) / EPB)   // 782
#define NSC 196          // scan blocks over nodes (196*256 = 50176 >= N)

#define QKVS0_BLKS 3125

// fused prep grid partition
#define LN0_BLKS   6250
#define DEG_BLKS   SB
#define WP0_BLKS   32    // 16*1*512 / 256
#define WP12_BLKS  64    // 16*2*512 / 256
#define PREP_BLKS  (LN0_BLKS + DEG_BLKS + WP0_BLKS + 2 * WP12_BLKS)

typedef __attribute__((ext_vector_type(8))) short short8;
typedef __attribute__((ext_vector_type(4))) float float4v;

__device__ __forceinline__ unsigned short f32_to_bf16_rne(float f) {
    unsigned int u = __float_as_uint(f);
    unsigned int r = u + 0x7fffu + ((u >> 16) & 1u);
    return (unsigned short)(r >> 16);
}

// ---------------------------------------------------------------------------
// Device helpers for the fused prep kernel.
__device__ __forceinline__ void ln0_body(int b, int t,
        const float* __restrict__ x, const float* __restrict__ g,
        const float* __restrict__ bb, float* __restrict__ h0) {
    int lane = t & 63;
    int n = b * 8 + (t >> 6) * 2 + (lane >> 5);
    int c = lane & 31;
    float v = x[n * 32 + c];
    float s = v;
    #pragma unroll
    for (int off = 1; off < 32; off <<= 1) s += __shfl_xor(s, off);
    float mu = s * (1.0f / 32.0f);
    float d = v - mu;
    float vs = d * d;
    #pragma unroll
    for (int off = 1; off < 32; off <<= 1) vs += __shfl_xor(vs, off);
    float var = vs * (1.0f / 32.0f);
    h0[n * 32 + c] = d * rsqrtf(var + 1e-5f) * g[c] + bb[c];
}

__device__ __forceinline__ void wprep_body(int idx, int KS,
        const float* __restrict__ Wq, const float* __restrict__ Wk,
        const float* __restrict__ Wv, const float* __restrict__ Ws,
        unsigned short* __restrict__ Wp) {
    int j = idx & 7;
    int lane = (idx >> 3) & 63;
    int ts = idx >> 9;            // tile*KS + s
    int s = ts % KS;
    int tile = ts / KS;
    int which = tile >> 2;
    int slice = tile & 3;
    int k = s * 32 + ((lane >> 4) * 8) + j;
    int col = slice * 16 + (lane & 15);
    const float* W = (which == 0) ? Wq : (which == 1) ? Wk : (which == 2) ? Wv : Ws;
    Wp[idx] = f32_to_bf16_rne(W[k * 64 + col]);
}

// ---------------------------------------------------------------------------
// Fused prep: ln0 + per-node degree count (global atomics) + 3x weight pack.
// R7: the bucket histogram is replaced by direct atomic deg — the whole
// ebkt round-trip + bucket_build kernel disappear downstream.
__global__ __launch_bounds__(256) void prep_kernel(
        const float* __restrict__ x, const float* __restrict__ ln0g,
        const float* __restrict__ ln0b, float* __restrict__ h0,
        const int* __restrict__ dst, int* __restrict__ deg,
        const float* __restrict__ Wq0, const float* __restrict__ Wk0,
        const float* __restrict__ Wv0, const float* __restrict__ Ws0,
        unsigned short* __restrict__ Wp0,
        const float* __restrict__ Wq1, const float* __restrict__ Wk1,
        const float* __restrict__ Wv1, const float* __restrict__ Ws1,
        unsigned short* __restrict__ Wp1,
        const float* __restrict__ Wq2, const float* __restrict__ Wk2,
        const float* __restrict__ Wv2, const float* __restrict__ Ws2,
        unsigned short* __restrict__ Wp2) {
    int b = blockIdx.x;
    int t = threadIdx.x;
    if (b < LN0_BLKS) {
        ln0_body(b, t, x, ln0g, ln0b, h0);
    } else if (b < LN0_BLKS + DEG_BLKS) {
        int i = b - LN0_BLKS;
        int e0 = i * EPB;
        #pragma unroll
        for (int r = 0; r < EPB / 256; r++) {
            int e = e0 + r * 256 + t;
            if (e < N_EDGES) atomicAdd(&deg[dst[e]], 1);
        }
    } else if (b < LN0_BLKS + DEG_BLKS + WP0_BLKS) {
        int idx = (b - LN0_BLKS - DEG_BLKS) * 256 + t;
        wprep_body(idx, 1, Wq0, Wk0, Wv0, Ws0, Wp0);
    } else if (b < LN0_BLKS + DEG_BLKS + WP0_BLKS + WP12_BLKS) {
        int idx = (b - LN0_BLKS - DEG_BLKS - WP0_BLKS) * 256 + t;
        wprep_body(idx, 2, Wq1, Wk1, Wv1, Ws1, Wp1);
    } else {
        int idx = (b - LN0_BLKS - DEG_BLKS - WP0_BLKS - WP12_BLKS) * 256 + t;
        wprep_body(idx, 2, Wq2, Wk2, Wv2, Ws2, Wp2);
    }
}

// ---------------------------------------------------------------------------
// Node-degree scan -> row_ptr (+ working copy cur). 50176 entries, 3 kernels.
__global__ void scanA_kernel(const int* __restrict__ deg, int* __restrict__ csum) {
    int n = blockIdx.x * 256 + threadIdx.x;
    int v = (n < N_NODES) ? deg[n] : 0;
    #pragma unroll
    for (int off = 1; off < 64; off <<= 1) v += __shfl_xor(v, off);
    __shared__ int ws[4];
    if ((threadIdx.x & 63) == 0) ws[threadIdx.x >> 6] = v;
    __syncthreads();
    if (threadIdx.x == 0) csum[blockIdx.x] = ws[0] + ws[1] + ws[2] + ws[3];
}

__global__ void scanB_kernel(const int* __restrict__ csum, int* __restrict__ coff,
                             int* __restrict__ row_ptr) {
    int lane = threadIdx.x;
    int carry = 0;
    for (int base = 0; base < NSC; base += 64) {
        int i = base + lane;
        int v = (i < NSC) ? csum[i] : 0;
        int incl = v;
        #pragma unroll
        for (int off = 1; off < 64; off <<= 1) {
            int tt = __shfl_up(incl, off);
            if (lane >= off) incl += tt;
        }
        if (i < NSC) coff[i] = carry + incl - v;
        carry += __shfl(incl, 63);
    }
    if (lane == 0) row_ptr[N_NODES] = N_EDGES;
}

__global__ void scanC_kernel(const int* __restrict__ deg, const int* __restrict__ coff,
                             int* __restrict__ row_ptr, int* __restrict__ cur) {
    int n = blockIdx.x * 256 + threadIdx.x;
    int lane = threadIdx.x & 63;
    int w = threadIdx.x >> 6;
    int v = (n < N_NODES) ? deg[n] : 0;
    int incl = v;
    #pragma unroll
    for (int off = 1; off < 64; off <<= 1) {
        int tt = __shfl_up(incl, off);
        if (lane >= off) incl += tt;
    }
    __shared__ int ws[4];
    if (lane == 63) ws[w] = incl;
    __syncthreads();
    int woff = 0;
    #pragma unroll
    for (int k = 0; k < 4; k++) if (k < w) woff += ws[k];
    int excl = coff[blockIdx.x] + woff + incl - v;
    if (n < N_NODES) {
        row_ptr[n] = excl;
        cur[n] = excl;
    }
}

// ---------------------------------------------------------------------------
// Q/K/V/Skip projection body via MFMA (R1-proven). Block = 16 nodes; wave w
// owns 16-col slice w of Q,K,V,S. Outputs packed bf16:
//   QS = (bf16(S)<<16)|bf16(Q*scale)   KV = (bf16(V)<<16)|bf16(K)
template <int D>
__device__ __forceinline__ void qkvs_body(int bid, int t,
        const float* __restrict__ h,
        const unsigned short* __restrict__ Wp,
        const float* __restrict__ bq, const float* __restrict__ bk,
        const float* __restrict__ bv, float scale,
        unsigned int* __restrict__ QS, unsigned int* __restrict__ KV) {
    constexpr int KS = D / 32;
    int lane = t & 63;
    int w = t >> 6;
    int n0 = bid * 16;
    int n16 = lane & 15;
    int quad = lane >> 4;
    int col = w * 16 + n16;

    short8 afrag[KS];
    #pragma unroll
    for (int s = 0; s < KS; s++) {
        const float* hp = &h[(n0 + n16) * D + s * 32 + quad * 8];
        float4 a0 = *(const float4*)hp;
        float4 a1 = *(const float4*)(hp + 4);
        short8 af;
        af[0] = (short)f32_to_bf16_rne(a0.x);
        af[1] = (short)f32_to_bf16_rne(a0.y);
        af[2] = (short)f32_to_bf16_rne(a0.z);
        af[3] = (short)f32_to_bf16_rne(a0.w);
        af[4] = (short)f32_to_bf16_rne(a1.x);
        af[5] = (short)f32_to_bf16_rne(a1.y);
        af[6] = (short)f32_to_bf16_rne(a1.z);
        af[7] = (short)f32_to_bf16_rne(a1.w);
        afrag[s] = af;
    }

    float4v accs[4];
    #pragma unroll
    for (int which = 0; which < 4; which++) {
        float4v acc = {0.0f, 0.0f, 0.0f, 0.0f};
        int tile = which * 4 + w;
        #pragma unroll
        for (int s = 0; s < KS; s++) {
            short8 bfrag = *(const short8*)&Wp[((tile * KS + s) * 64 + lane) * 8];
            acc = __builtin_amdgcn_mfma_f32_16x16x32_bf16(afrag[s], bfrag, acc, 0, 0, 0);
        }
        accs[which] = acc;
    }

    float bqc = bq[col], bkc = bk[col], bvc = bv[col];

    #pragma unroll
    for (int r = 0; r < 4; r++) {
        int node = n0 + quad * 4 + r;
        unsigned int qw = f32_to_bf16_rne((accs[0][r] + bqc) * scale);
        unsigned int sw = f32_to_bf16_rne(accs[3][r]);
        QS[node * 64 + col] = (sw << 16) | qw;
        unsigned int kw = f32_to_bf16_rne(accs[1][r] + bkc);
        unsigned int vw = f32_to_bf16_rne(accs[2][r] + bvc);
        KV[node * 64 + col] = (vw << 16) | kw;
    }
}

template <int D>
__global__ __launch_bounds__(256) void qkvs_mfma_kernel(
        const float* __restrict__ h,
        const unsigned short* __restrict__ Wp,
        const float* __restrict__ bq, const float* __restrict__ bk,
        const float* __restrict__ bv, float scale,
        unsigned int* __restrict__ QS, unsigned int* __restrict__ KV) {
    qkvs_body<D>(blockIdx.x, threadIdx.x, h, Wp, bq, bk, bv, scale, QS, KV);
}

// ---------------------------------------------------------------------------
// Fused direct-CSR scatter + layer-0 QKVS. Each edge goes straight to its
// final slot via atomicAdd on cur[dst] — no ebkt, no bucket_build.
__global__ __launch_bounds__(256) void scatter_qkvs0_kernel(
        const int* __restrict__ src, const int* __restrict__ dst,
        int* __restrict__ cur, int* __restrict__ colb,
        const float* __restrict__ h, const unsigned short* __restrict__ Wp,
        const float* __restrict__ bq, const float* __restrict__ bk,
        const float* __restrict__ bv, float scale,
        unsigned int* __restrict__ QS, unsigned int* __restrict__ KV) {
    int t = threadIdx.x;
    if (blockIdx.x < SB) {
        int e0 = blockIdx.x * EPB;
        #pragma unroll
        for (int r = 0; r < EPB / 256; r++) {
            int e = e0 + r * 256 + t;
            if (e < N_EDGES) {
                int s = src[e], d = dst[e];
                int slot = atomicAdd(&cur[d], 1);
                colb[slot] = s;
            }
        }
    } else {
        qkvs_body<32>(blockIdx.x - SB, t, h, Wp, bq, bk, bv, scale, QS, KV);
    }
}

// ---------------------------------------------------------------------------
// Per-node attention aggregation + skip + LayerNorm (+res/relu) — R1-proven
// structure (best measured: 324.4us total). One wave per node; 16-edge
// batched gathers; KV packed bf16 uint4 rows.
template <int HEADS, bool RES, bool RELU, bool HEAD>
__global__ __launch_bounds__(256) void agg_kernel(
                           const unsigned int* __restrict__ QS,
                           const unsigned int* __restrict__ KV,
                           const int* __restrict__ row_ptr, const int* __restrict__ colb,
                           const float* __restrict__ g, const float* __restrict__ b,
                           const float* __restrict__ h_in, float* __restrict__ h_out,
                           const float* __restrict__ Wr1, const float* __restrict__ br1,
                           const float* __restrict__ Wr2, const float* __restrict__ br2,
                           const float* __restrict__ Wt1, const float* __restrict__ bt1,
                           const float* __restrict__ Wt2, const float* __restrict__ bt2,
                           float* __restrict__ out) {
    constexpr int C = HID / HEADS;
    int lane = threadIdx.x & 63;
    int m = lane & 15;
    int grp = lane >> 4;
    int n = blockIdx.x * 4 + (threadIdx.x >> 6);

    uint4 qs = *(const uint4*)&QS[n * 64 + 4 * m];
    float4 q4 = make_float4(__uint_as_float(qs.x << 16),
                            __uint_as_float(qs.y << 16),
                            __uint_as_float(qs.z << 16),
                            __uint_as_float(qs.w << 16));

    int beg = row_ptr[n], end = row_ptr[n + 1];

    float ssum = 0.0f;
    float acc0 = 0.0f, acc1 = 0.0f, acc2 = 0.0f, acc3 = 0.0f;

    for (int base = beg; base < end; base += 64) {
        int limit = min(end - base, 64);
        int src_l = (base + lane < end) ? colb[base + lane] : 0;
        for (int sub = 0; sub < limit; sub += 16) {
            int e0 = sub + grp, e1 = sub + 4 + grp, e2 = sub + 8 + grp, e3 = sub + 12 + grp;
            int s0 = __shfl(src_l, e0);
            int s1 = __shfl(src_l, e1);
            int s2 = __shfl(src_l, e2);
            int s3 = __shfl(src_l, e3);
            bool v0ok = e0 < limit, v1ok = e1 < limit, v2ok = e2 < limit, v3ok = e3 < limit;
            uint4 kv0 = make_uint4(0, 0, 0, 0), kv1 = kv0, kv2 = kv0, kv3 = kv0;
            if (v0ok) kv0 = *(const uint4*)&KV[(size_t)s0 * 64 + 4 * m];
            if (v1ok) kv1 = *(const uint4*)&KV[(size_t)s1 * 64 + 4 * m];
            if (v2ok) kv2 = *(const uint4*)&KV[(size_t)s2 * 64 + 4 * m];
            if (v3ok) kv3 = *(const uint4*)&KV[(size_t)s3 * 64 + 4 * m];

            float t0 = fmaf(q4.x, __uint_as_float(kv0.x << 16),
                       fmaf(q4.y, __uint_as_float(kv0.y << 16),
                       fmaf(q4.z, __uint_as_float(kv0.z << 16),
                            q4.w * __uint_as_float(kv0.w << 16))));
            float t1 = fmaf(q4.x, __uint_as_float(kv1.x << 16),
                       fmaf(q4.y, __uint_as_float(kv1.y << 16),
                       fmaf(q4.z, __uint_as_float(kv1.z << 16),
                            q4.w * __uint_as_float(kv1.w << 16))));
            float t2 = fmaf(q4.x, __uint_as_float(kv2.x << 16),
                       fmaf(q4.y, __uint_as_float(kv2.y << 16),
                       fmaf(q4.z, __uint_as_float(kv2.z << 16),
                            q4.w * __uint_as_float(kv2.w << 16))));
            float t3 = fmaf(q4.x, __uint_as_float(kv3.x << 16),
                       fmaf(q4.y, __uint_as_float(kv3.y << 16),
                       fmaf(q4.z, __uint_as_float(kv3.z << 16),
                            q4.w * __uint_as_float(kv3.w << 16))));
            #pragma unroll
            for (int off = 1; off < C / 4; off <<= 1) {
                t0 += __shfl_xor(t0, off);
                t1 += __shfl_xor(t1, off);
                t2 += __shfl_xor(t2, off);
                t3 += __shfl_xor(t3, off);
            }
            float p0 = v0ok ? __expf(t0) : 0.0f;
            float p1 = v1ok ? __expf(t1) : 0.0f;
            float p2 = v2ok ? __expf(t2) : 0.0f;
            float p3 = v3ok ? __expf(t3) : 0.0f;
            ssum += (p0 + p1) + (p2 + p3);
            acc0 = fmaf(p0, __uint_as_float(kv0.x & 0xffff0000u),
                   fmaf(p1, __uint_as_float(kv1.x & 0xffff0000u),
                   fmaf(p2, __uint_as_float(kv2.x & 0xffff0000u),
                   fmaf(p3, __uint_as_float(kv3.x & 0xffff0000u), acc0))));
            acc1 = fmaf(p0, __uint_as_float(kv0.y & 0xffff0000u),
                   fmaf(p1, __uint_as_float(kv1.y & 0xffff0000u),
                   fmaf(p2, __uint_as_float(kv2.y & 0xffff0000u),
                   fmaf(p3, __uint_as_float(kv3.y & 0xffff0000u), acc1))));
            acc2 = fmaf(p0, __uint_as_float(kv0.z & 0xffff0000u),
                   fmaf(p1, __uint_as_float(kv1.z & 0xffff0000u),
                   fmaf(p2, __uint_as_float(kv2.z & 0xffff0000u),
                   fmaf(p3, __uint_as_float(kv3.z & 0xffff0000u), acc2))));
            acc3 = fmaf(p0, __uint_as_float(kv0.w & 0xffff0000u),
                   fmaf(p1, __uint_as_float(kv1.w & 0xffff0000u),
                   fmaf(p2, __uint_as_float(kv2.w & 0xffff0000u),
                   fmaf(p3, __uint_as_float(kv3.w & 0xffff0000u), acc3))));
        }
    }

    #pragma unroll
    for (int off = 16; off < 64; off <<= 1) {
        ssum += __shfl_xor(ssum, off);
        acc0 += __shfl_xor(acc0, off);
        acc1 += __shfl_xor(acc1, off);
        acc2 += __shfl_xor(acc2, off);
        acc3 += __shfl_xor(acc3, off);
    }

    float inv = 1.0f / (ssum + 1e-16f);
    float o0 = fmaf(acc0, inv, __uint_as_float(qs.x & 0xffff0000u));
    float o1 = fmaf(acc1, inv, __uint_as_float(qs.y & 0xffff0000u));
    float o2 = fmaf(acc2, inv, __uint_as_float(qs.z & 0xffff0000u));
    float o3 = fmaf(acc3, inv, __uint_as_float(qs.w & 0xffff0000u));

    float s = (o0 + o1) + (o2 + o3);
    #pragma unroll
    for (int off = 1; off < 16; off <<= 1) s += __shfl_xor(s, off);
    float mu = s * (1.0f / 64.0f);
    float d0 = o0 - mu, d1 = o1 - mu, d2 = o2 - mu, d3 = o3 - mu;
    float vs = (d0 * d0 + d1 * d1) + (d2 * d2 + d3 * d3);
    #pragma unroll
    for (int off = 1; off < 16; off <<= 1) vs += __shfl_xor(vs, off);
    float rstd = rsqrtf(vs * (1.0f / 64.0f) + 1e-5f);

    float4 gv = *(const float4*)&g[4 * m];
    float4 bv = *(const float4*)&b[4 * m];
    float y0 = d0 * rstd * gv.x + bv.x;
    float y1 = d1 * rstd * gv.y + bv.y;
    float y2 = d2 * rstd * gv.z + bv.z;
    float y3 = d3 * rstd * gv.w + bv.w;
    if (RES) {
        float4 rv = *(const float4*)&h_in[n * 64 + 4 * m];
        y0 = fmaf(0.1f, rv.x, y0);
        y1 = fmaf(0.1f, rv.y, y1);
        y2 = fmaf(0.1f, rv.z, y2);
        y3 = fmaf(0.1f, rv.w, y3);
    }
    if (RELU) {
        y0 = fmaxf(y0, 0.0f); y1 = fmaxf(y1, 0.0f);
        y2 = fmaxf(y2, 0.0f); y3 = fmaxf(y3, 0.0f);
    }

    if (!HEAD) {
        if (grp == 0) {
            float4 yv = make_float4(y0, y1, y2, y3);
            *(float4*)&h_out[n * 64 + 4 * m] = yv;
        }
    } else {
        __shared__ float sh[4][HID];
        int wave = threadIdx.x >> 6;
        if (grp == 0) {
            float4 yv = make_float4(y0, y1, y2, y3);
            *(float4*)&sh[wave][4 * m] = yv;
        }
        __syncthreads();
        int half = lane >> 5;
        int j = lane & 31;
        const float* W1 = half ? Wt1 : Wr1;
        const float* b1 = half ? bt1 : br1;
        const float* W2 = half ? Wt2 : Wr2;
        const float* b2v = half ? bt2 : br2;
        float a = b1[j];
        #pragma unroll 8
        for (int i = 0; i < 64; i++) a = fmaf(sh[wave][i], W1[i * 32 + j], a);
        a = fmaxf(a, 0.0f);
        float r = a * W2[j];
        #pragma unroll
        for (int off = 1; off < 32; off <<= 1) r += __shfl_xor(r, off);
        if (j == 0) out[n * 2 + half] = r + b2v[0];
    }
}

// ---------------------------------------------------------------------------
extern "C" void kernel_launch(void* const* d_in, const int* in_sizes, int n_in,
                              void* d_out, int out_size, void* d_ws, size_t ws_size,
                              hipStream_t stream) {
    const float* x    = (const float*)d_in[0];
    const int*   ei   = (const int*)d_in[1];
    const int*   src  = ei;
    const int*   dst  = ei + N_EDGES;
    const float* ln0g = (const float*)d_in[2];
    const float* ln0b = (const float*)d_in[3];

    const float* P[27];
    for (int i = 0; i < 27; i++) P[i] = (const float*)d_in[4 + i];
    const float* Wr1 = (const float*)d_in[31];
    const float* br1 = (const float*)d_in[32];
    const float* Wr2 = (const float*)d_in[33];
    const float* br2 = (const float*)d_in[34];
    const float* Wt1 = (const float*)d_in[35];
    const float* bt1 = (const float*)d_in[36];
    const float* Wt2 = (const float*)d_in[37];
    const float* bt2 = (const float*)d_in[38];

    float* out = (float*)d_out;

    // workspace layout
    float* hbuf0 = (float*)d_ws;                 // N*64
    float* hbuf1 = hbuf0 + N_NODES * 64;         // N*64
    unsigned int* QSb = (unsigned int*)(hbuf1 + N_NODES * 64); // N*64 uint
    unsigned int* KVb = QSb + N_NODES * 64;      // N*64 uint
    int* row_ptr = (int*)(KVb + N_NODES * 64);   // N+1
    int* cur     = row_ptr + (N_NODES + 1);      // N
    int* colb    = cur + N_NODES;                // E
    int* deg     = colb + N_EDGES;               // N
    int* csum    = deg + N_NODES;                // NSC
    int* coff    = csum + NSC;                   // NSC
    unsigned short* Wp0 = (unsigned short*)(coff + NSC);      // 16*1*512
    unsigned short* Wp1 = Wp0 + 16 * 1 * 512;                 // 16*2*512
    unsigned short* Wp2 = Wp1 + 16 * 2 * 512;                 // 16*2*512

    // deg must be zero before prep's atomics (harness itself uses
    // hipMemsetAsync during reset; it is graph-capture safe).
    hipMemsetAsync(deg, 0, N_NODES * sizeof(int), stream);

    // ---- fused prep (ln0 + atomic degree count + weight packs) ----
    prep_kernel<<<PREP_BLKS, 256, 0, stream>>>(x, ln0g, ln0b, hbuf0,
        dst, deg,
        P[0],  P[2],  P[4],  P[6],  Wp0,
        P[9],  P[11], P[13], P[15], Wp1,
        P[18], P[20], P[22], P[24], Wp2);
    // ---- row_ptr scan over node degrees (50k, 3 tiny kernels) ----
    scanA_kernel<<<NSC, 256, 0, stream>>>(deg, csum);
    scanB_kernel<<<1, 64, 0, stream>>>(csum, coff, row_ptr);
    scanC_kernel<<<NSC, 256, 0, stream>>>(deg, coff, row_ptr, cur);
    // ---- direct-CSR scatter + layer-0 QKVS fused ----
    scatter_qkvs0_kernel<<<SB + QKVS0_BLKS, 256, 0, stream>>>(src, dst, cur, colb,
        hbuf0, Wp0, P[1], P[3], P[5], 0.25f, QSb, KVb);

    // ---- layer 0: 32 -> 64, heads=4, no residual, relu ----
    agg_kernel<4, false, true, false><<<12500, 256, 0, stream>>>(QSb, KVb,
        row_ptr, colb, P[7], P[8], nullptr, hbuf1,
        Wr1, br1, Wr2, br2, Wt1, bt1, Wt2, bt2, out);

    // ---- layer 1: 64 -> 64, heads=4, residual, relu ----
    qkvs_mfma_kernel<64><<<3125, 256, 0, stream>>>(hbuf1, Wp1,
        P[10], P[12], P[14], 0.25f, QSb, KVb);
    agg_kernel<4, true, true, false><<<12500, 256, 0, stream>>>(QSb, KVb,
        row_ptr, colb, P[16], P[17], hbuf1, hbuf0,
        Wr1, br1, Wr2, br2, Wt1, bt1, Wt2, bt2, out);

    // ---- layer 2: 64 -> 64, heads=1, residual, no relu + fused MLP heads ----
    qkvs_mfma_kernel<64><<<3125, 256, 0, stream>>>(hbuf0, Wp2,
        P[19], P[21], P[23], 0.125f, QSb, KVb);
    agg_kernel<1, true, false, true><<<12500, 256, 0, stream>>>(QSb, KVb,
        row_ptr, colb, P[25], P[26], hbuf0, hbuf1,
        Wr1, br1, Wr2, br2, Wt1, bt1, Wt2, bt2, out);
}